// Round 5
// baseline (243.584 us; speedup 1.0000x reference)
//
#include <hip/hip_runtime.h>
#include <math.h>

#define BATCH 2
#define SEQ   2048
#define DM    1024
#define NH    16
#define HD    64
#define MTOT  (BATCH*SEQ)            // 4096

typedef short v8s __attribute__((ext_vector_type(8)));   // 8 bf16 = 4 VGPR
typedef short v4s __attribute__((ext_vector_type(4)));
typedef float v4f __attribute__((ext_vector_type(4)));

#define MFMA16(a, b, c) __builtin_amdgcn_mfma_f32_16x16x32_bf16((a), (b), (c), 0, 0, 0)

__device__ __forceinline__ short f2b(float f) {   // fp32->bf16, round-half-up
    union { float f; unsigned u; } v; v.f = f;
    return (short)((v.u + 0x8000u) >> 16);
}

// raw v_exp_f32 (exp2): OCML exp2f adds a denormal-guard sequence (~6 instr);
// the hot softmax path only needs the HW instruction. exp2(-1e30) -> 0 in HW.
__device__ __forceinline__ float fexp2(float x) {
    float r; asm("v_exp_f32 %0, %1" : "=v"(r) : "v"(x)); return r;
}

// async global->LDS, 16B per lane. dst must be wave-uniform base; HW adds lane*16.
__device__ __forceinline__ void gload16(const void* g, void* lds) {
    __builtin_amdgcn_global_load_lds(
        (const __attribute__((address_space(1))) void*)g,
        (__attribute__((address_space(3))) void*)lds, 16, 0, 0);
}

// native RoPE sincos via revolutions + fract (no library range reduction)
__device__ __forceinline__ void rope_cs(int n, float f_rev, float* c, float* s) {
    float rev = (float)n * f_rev;
    float t = rev - floorf(rev);
    float ang = t * 6.283185307179586f;
    *c = __cosf(ang);
    *s = __sinf(ang);
}

#define L2_1E4_D32 0.4152410118609203f   // log2(10000)/32
#define INV2PI     0.15915494309189535f
#define QSCALE     0.18033688011112042f  // 0.125 * log2(e)

// ---------------------------------------------------------------------------
// Kernel 0: fused fp32 -> bf16 convert for x | Wq | Wk | Wv | Wo into ws base.
// ---------------------------------------------------------------------------
__global__ __launch_bounds__(256) void cvt_all_kernel(
    const float* __restrict__ x,  const float* __restrict__ wq,
    const float* __restrict__ wk, const float* __restrict__ wv,
    const float* __restrict__ wo, short* __restrict__ dst)
{
    int i = blockIdx.x * 256 + threadIdx.x;            // < 1 Mi
    const float* src; int off;
    if (i < (1 << 19)) { src = x; off = i; }
    else {
        int j = i - (1 << 19);
        int wsel = j >> 17;
        off = j & ((1 << 17) - 1);
        src = (wsel == 0) ? wq : (wsel == 1) ? wk : (wsel == 2) ? wv : wo;
    }
    const float4* s4 = (const float4*)src;
    float4 a = s4[2 * off], b = s4[2 * off + 1];
    v8s p;
    p[0] = f2b(a.x); p[1] = f2b(a.y); p[2] = f2b(a.z); p[3] = f2b(a.w);
    p[4] = f2b(b.x); p[5] = f2b(b.y); p[6] = f2b(b.z); p[7] = f2b(b.w);
    *(v8s*)&dst[8 * i] = p;
}

// ---------------------------------------------------------------------------
// Kernel 1: Q/K/V projections, 128x128 MFMA tile. Native-sincos RoPE.
// Round-3 structure RESTORED: single-buffer + 2 barriers. Round-4's explicit
// dbuf was neutral-negative: __syncthreads() emits vmcnt(0) which drains the
// just-issued prefetch anyway (m99/m100 null) — do not re-add without
// counted-vmcnt + raw s_barrier.
//   z=0: K = RoPE(x @ Wk^T)        -> [bh][key][d]
//   z=1: V = x @ Wv^T (transposed) -> Vt[bh][d][key]
//   z=2: Q = QSCALE*RoPE(x @ Wq^T) -> Qb[bh][row][d]
// grid = (MTOT/128, DM/128, 3) = 768 blocks, 3/CU.
// ---------------------------------------------------------------------------
__global__ __launch_bounds__(256, 3) void qkv_rope_mfma(
    const short* __restrict__ xb, const short* __restrict__ Wqb,
    const short* __restrict__ Wkb, const short* __restrict__ Wvb,
    short* __restrict__ K, short* __restrict__ Vt, short* __restrict__ Qb)
{
    const int zz = blockIdx.z;
    const short* __restrict__ Wb = (zz == 0) ? Wkb : (zz == 1) ? Wvb : Wqb;
    const int m0 = blockIdx.x * 128, e00 = blockIdx.y * 128;
    const int tid = threadIdx.x;
    const int w = tid >> 6, lane = tid & 63, lq = lane >> 4, lr = lane & 15;
    const int wm = w >> 1, wn = w & 1;

    __shared__ union {
        struct { short As[128][32]; short Bs[128][32]; } p1;  // 16 KB
        short Css[128][136];                                   // 34 KB
    } u;

    v4f acc[4][4];
    #pragma unroll
    for (int i = 0; i < 4; ++i)
        for (int j = 0; j < 4; ++j)
            for (int r = 0; r < 4; ++r) acc[i][j][r] = 0.f;

    const int gr = lane >> 2, gc = 8 * (lane & 3);
    for (int k0 = 0; k0 < DM; k0 += 32) {
        __syncthreads();   // prev iter LDS reads done
        gload16(&xb[(size_t)(m0 + 32 * w      + gr) * DM + k0 + gc], &u.p1.As[32 * w][0]);
        gload16(&xb[(size_t)(m0 + 32 * w + 16 + gr) * DM + k0 + gc], &u.p1.As[32 * w + 16][0]);
        gload16(&Wb[(size_t)(e00 + 32 * w      + gr) * DM + k0 + gc], &u.p1.Bs[32 * w][0]);
        gload16(&Wb[(size_t)(e00 + 32 * w + 16 + gr) * DM + k0 + gc], &u.p1.Bs[32 * w + 16][0]);
        __syncthreads();   // vmcnt drained before barrier -> tile visible
        v8s af[4], bf[4];
        #pragma unroll
        for (int i = 0; i < 4; ++i)
            af[i] = *(const v8s*)&u.p1.As[64 * wm + 16 * i + lr][8 * lq];
        #pragma unroll
        for (int j = 0; j < 4; ++j)
            bf[j] = *(const v8s*)&u.p1.Bs[64 * wn + 16 * j + lr][8 * lq];
        #pragma unroll
        for (int i = 0; i < 4; ++i)
            #pragma unroll
            for (int j = 0; j < 4; ++j)
                acc[i][j] = MFMA16(af[i], bf[j], acc[i][j]);
    }
    __syncthreads();   // k-loop LDS reads done before Css overwrite

    const int b = m0 >> 11, n00 = m0 & (SEQ - 1);

    if (zz != 1) {
        // RoPE in-register (cols of this wave = one head; pairs nt <-> nt^2)
        short* __restrict__ dst = (zz == 0) ? K : Qb;
        const float sc = (zz == 0) ? 1.0f : QSCALE;
        float f0 = exp2f(-(float)lr * L2_1E4_D32) * INV2PI;
        float f1 = exp2f(-(float)(16 + lr) * L2_1E4_D32) * INV2PI;
        #pragma unroll
        for (int i = 0; i < 4; ++i) {
            #pragma unroll
            for (int r = 0; r < 4; ++r) {
                int row = 64 * wm + 16 * i + 4 * lq + r;
                int n = n00 + row;
                float c0v, s0v, c1v, s1v;
                rope_cs(n, f0, &c0v, &s0v);
                rope_cs(n, f1, &c1v, &s1v);
                float q0 = acc[i][0][r], q1 = acc[i][1][r];
                float q2 = acc[i][2][r], q3 = acc[i][3][r];
                u.Css[row][64 * wn + lr]      = f2b(sc * (q0 * c0v - q2 * s0v));
                u.Css[row][64 * wn + 16 + lr] = f2b(sc * (q1 * c1v - q3 * s1v));
                u.Css[row][64 * wn + 32 + lr] = f2b(sc * (q2 * c0v + q0 * s0v));
                u.Css[row][64 * wn + 48 + lr] = f2b(sc * (q3 * c1v + q1 * s1v));
            }
        }
        __syncthreads();
        int row = tid >> 1, hh = tid & 1;
        int h = (e00 >> 6) + hh;
        int n = n00 + row;
        size_t base = (((size_t)(b * NH + h)) * SEQ + n) * HD;
        #pragma unroll
        for (int p = 0; p < 8; ++p)
            *(v8s*)&dst[base + 8 * p] = *(const v8s*)&u.Css[row][64 * hh + 8 * p];
    } else {
        // V transposed: Css_T[col][row], packed b64 along row (r contiguous)
        #pragma unroll
        for (int i = 0; i < 4; ++i) {
            #pragma unroll
            for (int j = 0; j < 4; ++j) {
                v4s t;
                #pragma unroll
                for (int r = 0; r < 4; ++r) t[r] = f2b(acc[i][j][r]);
                *(v4s*)&u.Css[64 * wn + 16 * j + lr][64 * wm + 16 * i + 4 * lq] = t;
            }
        }
        __syncthreads();
        int c = tid >> 1, half = (tid & 1) * 64;
        int h = (e00 + c) >> 6, d = (e00 + c) & 63;
        size_t base = (((size_t)(b * NH + h)) * HD + d) * SEQ + n00 + half;
        #pragma unroll
        for (int p = 0; p < 8; ++p)
            *(v8s*)&Vt[base + 8 * p] = *(const v8s*)&u.Css[c][half + 8 * p];
    }
}

// ---------------------------------------------------------------------------
// Kernel 2: flash attention, KEY-SPLIT wave decomposition (round-5).
// 8 waves = 4 row-groups (wr) x 2 key-groups (wk): each wave owns 32 Q-rows x
// its 64-key half per 128-key chunk. This HALVES the two dominant LDS pools
// (K-fragment reads and V-fragment reads: 16 -> 8 b128/wave/chunk each) —
// round-3 counters showed the kernel is LDS-pipe-bound (base LDS + conflicts
// ~= whole duration). O and row-sums become key-partial; merged once at the
// end through LDS scratch (Ps/Ks reuse after a barrier).
// Kept: T2 XOR-swizzle, key-permuted staging, fixed-max softmax (M=24),
// raw v_exp_f32, v_cvt_pk_bf16_f32, register prefetch.
// VGPR budget: nt processed in pairs (ntp) so kf/sv are 16-reg transients;
// persistent = o(32) + aq(16) + prefetch(16) + lacc(8). Target <=128 for
// 2 blocks/CU (LDS 64.5KB also caps at 2) = 16 waves/CU.
// launch_bounds min-waves stays 4 (cap 128): round-1 showed (512,6)'s cap-85
// causes catastrophic spills. WRITE_SIZE >> 9216 next round = spill signal.
// grid = (MTOT/128, NH) = 512 blocks.
// ---------------------------------------------------------------------------
#define SWZ(tile, row, bo) ((char*)&(tile)[row][0] + ((bo) ^ (((row) & 7) << 4)))

__global__ __launch_bounds__(512, 4) void attn_mfma(
    const short* __restrict__ Qb, const short* __restrict__ K,
    const short* __restrict__ Vt, const int* __restrict__ mask,
    short* __restrict__ O)
{
    const int m0 = blockIdx.x * 128, h = blockIdx.y;
    const int b = m0 >> 11, n0 = m0 & (SEQ - 1), bh = b * NH + h;
    const int tid = threadIdx.x;
    const int w = tid >> 6, lane = tid & 63, lq = lane >> 4, lr = lane & 15;
    const int wr = w >> 1, wk = w & 1;

    __shared__ short Ks[128][64];    // 16 KB, XOR-swizzled (key-permuted rows)
    __shared__ short Vs[64][128];    // 16 KB, XOR-swizzled ([d][128 true keys])
    __shared__ short Ps[128][128];   // 32 KB, XOR-swizzled ([qrow][128 true keys])
    __shared__ float mbias[128];     // 512 B, indexed by permuted storage row

    // ---- load Q A-fragments: rows 32wr+16it+lr, pre-scaled + RoPE'd ----
    const short* __restrict__ Qh = Qb + (size_t)bh * SEQ * HD;
    v8s aq[2][2];
    #pragma unroll
    for (int it = 0; it < 2; ++it)
        #pragma unroll
        for (int ks = 0; ks < 2; ++ks)
            aq[it][ks] = *(const v8s*)&Qh[(size_t)(n0 + 32 * wr + 16 * it + lr) * HD
                                          + 32 * ks + 8 * lq];

    float lacc[2][4];
    v4f o[2][4];
    #pragma unroll
    for (int it = 0; it < 2; ++it)
        #pragma unroll
        for (int nt = 0; nt < 4; ++nt) {
            lacc[it][nt] = 0.f;
            for (int r = 0; r < 4; ++r) o[it][nt][r] = 0.f;
        }

    // staging indices: K 128 rows x 64 d ; V 64 d x 128 keys (all waves stage)
    const int kr = tid >> 2, kc = (tid & 3) * 16;     // kc in shorts (global)
    const int kb = 32 * (tid & 3);                    // LDS byte offset
    const int krh = kr & 63;
    const int pkr = 64 * (kr >> 6) + 16 * (krh & 3) + (krh >> 2);  // permuted
    const int vr = tid >> 3, vc = (tid & 7) * 16;
    const int vb = 32 * (tid & 7);
    const short* __restrict__ Kb = K + (size_t)bh * SEQ * HD;
    const short* __restrict__ Vb = Vt + (size_t)bh * HD * SEQ;

    // prefetch chunk 0
    v8s k1 = *(const v8s*)&Kb[(size_t)kr * HD + kc];
    v8s k2 = *(const v8s*)&Kb[(size_t)kr * HD + kc + 8];
    v8s v1 = *(const v8s*)&Vb[(size_t)vr * SEQ + vc];
    v8s v2 = *(const v8s*)&Vb[(size_t)vr * SEQ + vc + 8];
    int mnext = ((tid & 3) == 0) ? mask[b * SEQ + kr] : 0;

    for (int c0 = 0; c0 < SEQ; c0 += 128) {
        __syncthreads();                      // prev chunk LDS reads done
        *(v8s*)SWZ(Ks, pkr, kb)      = k1;
        *(v8s*)SWZ(Ks, pkr, kb + 16) = k2;
        *(v8s*)SWZ(Vs, vr, vb)       = v1;
        *(v8s*)SWZ(Vs, vr, vb + 16)  = v2;
        if ((tid & 3) == 0) mbias[pkr] = mnext ? -24.0f : -1e30f;
        __syncthreads();
        if (c0 + 128 < SEQ) {                 // prefetch next chunk
            k1 = *(const v8s*)&Kb[(size_t)(c0 + 128 + kr) * HD + kc];
            k2 = *(const v8s*)&Kb[(size_t)(c0 + 128 + kr) * HD + kc + 8];
            v1 = *(const v8s*)&Vb[(size_t)vr * SEQ + c0 + 128 + vc];
            v2 = *(const v8s*)&Vb[(size_t)vr * SEQ + c0 + 128 + vc + 8];
            if ((tid & 3) == 0) mnext = mask[b * SEQ + c0 + 128 + kr];
        }

        // ---- QK^T + P for this wave's 64-key half, nt in pairs ----
        // storage row 64wk+16nt+lr holds key 64wk+4lr+nt (permutation);
        // S col (nt,lr) <-> true key 64wk+4lr+nt.
        #pragma unroll
        for (int ntp = 0; ntp < 2; ++ntp) {
            v8s kf0[2], kf1[2];
            #pragma unroll
            for (int ks = 0; ks < 2; ++ks) {
                kf0[ks] = *(const v8s*)SWZ(Ks, 64 * wk + 32 * ntp + lr,
                                           64 * ks + 16 * lq);
                kf1[ks] = *(const v8s*)SWZ(Ks, 64 * wk + 32 * ntp + 16 + lr,
                                           64 * ks + 16 * lq);
            }
            float bias0 = mbias[64 * wk + 32 * ntp + lr];
            float bias1 = mbias[64 * wk + 32 * ntp + 16 + lr];
            #pragma unroll
            for (int it = 0; it < 2; ++it) {
                v4f s0, s1;
                #pragma unroll
                for (int r = 0; r < 4; ++r) { s0[r] = 0.f; s1[r] = 0.f; }
                #pragma unroll
                for (int ks = 0; ks < 2; ++ks) {
                    s0 = MFMA16(aq[it][ks], kf0[ks], s0);
                    s1 = MFMA16(aq[it][ks], kf1[ks], s1);
                }
                // p = exp2(s + bias); 4B packed write: keys 4lr+2ntp, +1
                #pragma unroll
                for (int r = 0; r < 4; ++r) {
                    float p0 = fexp2(s0[r] + bias0);
                    float p1 = fexp2(s1[r] + bias1);
                    lacc[it][r] += p0 + p1;
                    unsigned uu;
                    asm("v_cvt_pk_bf16_f32 %0, %1, %2" : "=v"(uu) : "v"(p0), "v"(p1));
                    int qrow = 32 * wr + 16 * it + 4 * lq + r;
                    *(unsigned*)SWZ(Ps, qrow, 128 * wk + 8 * lr + 4 * ntp) = uu;
                }
            }
        }

        // ---- O += P @ V over this wave's 64 keys (Ps rows wave-owned) ----
        #pragma unroll
        for (int ks = 0; ks < 2; ++ks) {
            v8s a0 = *(const v8s*)SWZ(Ps, 32 * wr + lr,
                                      128 * wk + 64 * ks + 16 * lq);
            v8s a1 = *(const v8s*)SWZ(Ps, 32 * wr + 16 + lr,
                                      128 * wk + 64 * ks + 16 * lq);
            #pragma unroll
            for (int nt = 0; nt < 4; ++nt) {
                v8s vf = *(const v8s*)SWZ(Vs, 16 * nt + lr,
                                          128 * wk + 64 * ks + 16 * lq);
                o[0][nt] = MFMA16(a0, vf, o[0][nt]);
                o[1][nt] = MFMA16(a1, vf, o[1][nt]);
            }
        }
    }

    // ---- intra-wave row sums over this wave's keys (lanes lr 0..15) ----
    #pragma unroll
    for (int it = 0; it < 2; ++it)
        #pragma unroll
        for (int r = 0; r < 4; ++r) {
            float l = lacc[it][r];
            l += __shfl_xor(l, 1);
            l += __shfl_xor(l, 2);
            l += __shfl_xor(l, 4);
            l += __shfl_xor(l, 8);
            lacc[it][r] = l;
        }

    // ---- cross-wk merge through LDS scratch (Ps/Ks reuse) ----
    __syncthreads();                          // all PV reads finished
    float* mO = (float*)&Ps[0][0];            // 4wr x 8tile x 64lane x v4f = 32 KB
    float* mL = (float*)&Ks[0][0];            // 4wr x 8 x 64lane f32     =  8 KB
    if (wk == 1) {
        #pragma unroll
        for (int it = 0; it < 2; ++it) {
            #pragma unroll
            for (int nt = 0; nt < 4; ++nt)
                *(v4f*)&mO[(((wr * 8 + it * 4 + nt) * 64) + lane) * 4] = o[it][nt];
            #pragma unroll
            for (int r = 0; r < 4; ++r)
                mL[(wr * 8 + it * 4 + r) * 64 + lane] = lacc[it][r];
        }
    }
    __syncthreads();
    if (wk == 0) {
        #pragma unroll
        for (int it = 0; it < 2; ++it) {
            #pragma unroll
            for (int nt = 0; nt < 4; ++nt) {
                v4f t = *(const v4f*)&mO[(((wr * 8 + it * 4 + nt) * 64) + lane) * 4];
                #pragma unroll
                for (int r = 0; r < 4; ++r) o[it][nt][r] += t[r];
            }
            #pragma unroll
            for (int r = 0; r < 4; ++r) {
                float l = lacc[it][r] + mL[(wr * 8 + it * 4 + r) * 64 + lane];
                float inv = (l > 0.f) ? 1.f / l : 0.f;   // all-masked rows -> 0
                int qrow = 32 * wr + 16 * it + 4 * lq + r;
                #pragma unroll
                for (int nt = 0; nt < 4; ++nt)
                    O[(size_t)(m0 + qrow) * DM + h * HD + 16 * nt + lr] =
                        f2b(o[it][nt][r] * inv);
            }
        }
    }
}

// ---------------------------------------------------------------------------
// Kernel 3: out = O @ Wo^T, 64x128 MFMA tile (512 blocks), fp32 store.
// Round-3 structure restored (single-buffer; dbuf was neutral — see kernel 1).
// grid = (MTOT/64, DM/128).
// ---------------------------------------------------------------------------
__global__ __launch_bounds__(256, 2) void oproj_mfma(
    const short* __restrict__ O, const short* __restrict__ Wob,
    float* __restrict__ out)
{
    const int m0 = blockIdx.x * 64, e00 = blockIdx.y * 128;
    const int tid = threadIdx.x;
    const int w = tid >> 6, lane = tid & 63, lq = lane >> 4, lr = lane & 15;

    __shared__ short As[64][32];    // 4 KB
    __shared__ short Bs[128][32];   // 8 KB

    v4f acc[4][2];
    #pragma unroll
    for (int i = 0; i < 4; ++i)
        for (int j = 0; j < 2; ++j)
            for (int r = 0; r < 4; ++r) acc[i][j][r] = 0.f;

    const int gr = lane >> 2, gc = 8 * (lane & 3);
    for (int k0 = 0; k0 < DM; k0 += 32) {
        __syncthreads();
        gload16(&O[(size_t)(m0 + 16 * w + gr) * DM + k0 + gc],         &As[16 * w][0]);
        gload16(&Wob[(size_t)(e00 + 32 * w      + gr) * DM + k0 + gc], &Bs[32 * w][0]);
        gload16(&Wob[(size_t)(e00 + 32 * w + 16 + gr) * DM + k0 + gc], &Bs[32 * w + 16][0]);
        __syncthreads();
        v8s af[4], bf[2];
        #pragma unroll
        for (int i = 0; i < 4; ++i)
            af[i] = *(const v8s*)&As[16 * i + lr][8 * lq];
        #pragma unroll
        for (int j = 0; j < 2; ++j)
            bf[j] = *(const v8s*)&Bs[32 * w + 16 * j + lr][8 * lq];
        #pragma unroll
        for (int i = 0; i < 4; ++i)
            #pragma unroll
            for (int j = 0; j < 2; ++j)
                acc[i][j] = MFMA16(af[i], bf[j], acc[i][j]);
    }

    #pragma unroll
    for (int i = 0; i < 4; ++i)
        #pragma unroll
        for (int r = 0; r < 4; ++r) {
            int m = m0 + 16 * i + 4 * lq + r;
            #pragma unroll
            for (int j = 0; j < 2; ++j)
                out[(size_t)m * DM + e00 + 32 * w + 16 * j + lr] = acc[i][j][r];
        }
}

// ---------------------------------------------------------------------------
extern "C" void kernel_launch(void* const* d_in, const int* in_sizes, int n_in,
                              void* d_out, int out_size, void* d_ws, size_t ws_size,
                              hipStream_t stream)
{
    const float* x    = (const float*)d_in[0];
    const int*   mask = (const int*)d_in[1];
    const float* Wq   = (const float*)d_in[2];
    const float* Wk   = (const float*)d_in[3];
    const float* Wv   = (const float*)d_in[4];
    const float* Wo   = (const float*)d_in[5];
    float* out = (float*)d_out;

    // ws (24 MiB of shorts): xb | Wqb | Wkb | Wvb | Wob | Qb
    //   xb region is reused for O after qkv_rope (attn no longer reads x).
    short* xb  = (short*)d_ws;                    // 8 MB (x, then O)
    short* Wqb = xb  + (size_t)MTOT * DM;         // 2 MB each
    short* Wkb = Wqb + (size_t)DM * DM;
    short* Wvb = Wkb + (size_t)DM * DM;
    short* Wob = Wvb + (size_t)DM * DM;
    short* Qb  = Wob + (size_t)DM * DM;           // 8 MB
    short* O   = xb;                              // alias (post-qkv)
    // d_out (16 MiB) doubles as K/Vt scratch until the final projection
    short* K  = (short*)d_out;                    // 8 MB
    short* Vt = K + (size_t)MTOT * DM;            // 8 MB

    cvt_all_kernel<<<4096, 256, 0, stream>>>(x, Wq, Wk, Wv, Wo, xb);

    dim3 g1(MTOT / 128, DM / 128, 3);
    qkv_rope_mfma<<<g1, 256, 0, stream>>>(xb, Wqb, Wkb, Wvb, K, Vt, Qb);

    dim3 g2(MTOT / 128, NH);
    attn_mfma<<<g2, 512, 0, stream>>>(Qb, K, Vt, mask, O);

    dim3 g3(MTOT / 64, DM / 128);
    oproj_mfma<<<g3, 256, 0, stream>>>(O, Wob, out);
}

// Round 6
// 195.524 us; speedup vs baseline: 1.2458x; 1.2458x over previous
//
#include <hip/hip_runtime.h>
#include <math.h>

#define BATCH 2
#define SEQ   2048
#define DM    1024
#define NH    16
#define HD    64
#define MTOT  (BATCH*SEQ)            // 4096

typedef short v8s __attribute__((ext_vector_type(8)));   // 8 bf16 = 4 VGPR
typedef short v4s __attribute__((ext_vector_type(4)));
typedef float v4f __attribute__((ext_vector_type(4)));

#define MFMA16(a, b, c) __builtin_amdgcn_mfma_f32_16x16x32_bf16((a), (b), (c), 0, 0, 0)

__device__ __forceinline__ short f2b(float f) {   // fp32->bf16, round-half-up
    union { float f; unsigned u; } v; v.f = f;
    return (short)((v.u + 0x8000u) >> 16);
}

// raw v_exp_f32 (exp2): OCML exp2f adds a denormal-guard sequence (~6 instr);
// the hot softmax path only needs the HW instruction. exp2(-1e30) -> 0 in HW.
__device__ __forceinline__ float fexp2(float x) {
    float r; asm("v_exp_f32 %0, %1" : "=v"(r) : "v"(x)); return r;
}

// async global->LDS, 16B per lane. dst must be wave-uniform base; HW adds lane*16.
__device__ __forceinline__ void gload16(const void* g, void* lds) {
    __builtin_amdgcn_global_load_lds(
        (const __attribute__((address_space(1))) void*)g,
        (__attribute__((address_space(3))) void*)lds, 16, 0, 0);
}

// native RoPE sincos via revolutions + fract (no library range reduction)
__device__ __forceinline__ void rope_cs(int n, float f_rev, float* c, float* s) {
    float rev = (float)n * f_rev;
    float t = rev - floorf(rev);
    float ang = t * 6.283185307179586f;
    *c = __cosf(ang);
    *s = __sinf(ang);
}

#define L2_1E4_D32 0.4152410118609203f   // log2(10000)/32
#define INV2PI     0.15915494309189535f
#define QSCALE     0.18033688011112042f  // 0.125 * log2(e)

// ---------------------------------------------------------------------------
// Kernel 0: fused fp32 -> bf16 convert for x | Wq | Wk | Wv | Wo into ws base.
// ---------------------------------------------------------------------------
__global__ __launch_bounds__(256) void cvt_all_kernel(
    const float* __restrict__ x,  const float* __restrict__ wq,
    const float* __restrict__ wk, const float* __restrict__ wv,
    const float* __restrict__ wo, short* __restrict__ dst)
{
    int i = blockIdx.x * 256 + threadIdx.x;            // < 1 Mi
    const float* src; int off;
    if (i < (1 << 19)) { src = x; off = i; }
    else {
        int j = i - (1 << 19);
        int wsel = j >> 17;
        off = j & ((1 << 17) - 1);
        src = (wsel == 0) ? wq : (wsel == 1) ? wk : (wsel == 2) ? wv : wo;
    }
    const float4* s4 = (const float4*)src;
    float4 a = s4[2 * off], b = s4[2 * off + 1];
    v8s p;
    p[0] = f2b(a.x); p[1] = f2b(a.y); p[2] = f2b(a.z); p[3] = f2b(a.w);
    p[4] = f2b(b.x); p[5] = f2b(b.y); p[6] = f2b(b.z); p[7] = f2b(b.w);
    *(v8s*)&dst[8 * i] = p;
}

// ---------------------------------------------------------------------------
// Kernel 1: Q/K/V projections, 128x128 MFMA tile. Native-sincos RoPE.
// Round-3 structure (single-buffer + 2 barriers). Round-4's explicit dbuf was
// neutral-negative: __syncthreads() emits vmcnt(0) which drains the
// just-issued prefetch anyway (m99/m100 null).
//   z=0: K = RoPE(x @ Wk^T)        -> [bh][key][d]
//   z=1: V = x @ Wv^T (transposed) -> Vt[bh][d][key]
//   z=2: Q = QSCALE*RoPE(x @ Wq^T) -> Qb[bh][row][d]
// grid = (MTOT/128, DM/128, 3) = 768 blocks, 3/CU.
// ---------------------------------------------------------------------------
__global__ __launch_bounds__(256, 3) void qkv_rope_mfma(
    const short* __restrict__ xb, const short* __restrict__ Wqb,
    const short* __restrict__ Wkb, const short* __restrict__ Wvb,
    short* __restrict__ K, short* __restrict__ Vt, short* __restrict__ Qb)
{
    const int zz = blockIdx.z;
    const short* __restrict__ Wb = (zz == 0) ? Wkb : (zz == 1) ? Wvb : Wqb;
    const int m0 = blockIdx.x * 128, e00 = blockIdx.y * 128;
    const int tid = threadIdx.x;
    const int w = tid >> 6, lane = tid & 63, lq = lane >> 4, lr = lane & 15;
    const int wm = w >> 1, wn = w & 1;

    __shared__ union {
        struct { short As[128][32]; short Bs[128][32]; } p1;  // 16 KB
        short Css[128][136];                                   // 34 KB
    } u;

    v4f acc[4][4];
    #pragma unroll
    for (int i = 0; i < 4; ++i)
        for (int j = 0; j < 4; ++j)
            for (int r = 0; r < 4; ++r) acc[i][j][r] = 0.f;

    const int gr = lane >> 2, gc = 8 * (lane & 3);
    for (int k0 = 0; k0 < DM; k0 += 32) {
        __syncthreads();   // prev iter LDS reads done
        gload16(&xb[(size_t)(m0 + 32 * w      + gr) * DM + k0 + gc], &u.p1.As[32 * w][0]);
        gload16(&xb[(size_t)(m0 + 32 * w + 16 + gr) * DM + k0 + gc], &u.p1.As[32 * w + 16][0]);
        gload16(&Wb[(size_t)(e00 + 32 * w      + gr) * DM + k0 + gc], &u.p1.Bs[32 * w][0]);
        gload16(&Wb[(size_t)(e00 + 32 * w + 16 + gr) * DM + k0 + gc], &u.p1.Bs[32 * w + 16][0]);
        __syncthreads();   // vmcnt drained before barrier -> tile visible
        v8s af[4], bf[4];
        #pragma unroll
        for (int i = 0; i < 4; ++i)
            af[i] = *(const v8s*)&u.p1.As[64 * wm + 16 * i + lr][8 * lq];
        #pragma unroll
        for (int j = 0; j < 4; ++j)
            bf[j] = *(const v8s*)&u.p1.Bs[64 * wn + 16 * j + lr][8 * lq];
        #pragma unroll
        for (int i = 0; i < 4; ++i)
            #pragma unroll
            for (int j = 0; j < 4; ++j)
                acc[i][j] = MFMA16(af[i], bf[j], acc[i][j]);
    }
    __syncthreads();   // k-loop LDS reads done before Css overwrite

    const int b = m0 >> 11, n00 = m0 & (SEQ - 1);

    if (zz != 1) {
        // RoPE in-register (cols of this wave = one head; pairs nt <-> nt^2)
        short* __restrict__ dst = (zz == 0) ? K : Qb;
        const float sc = (zz == 0) ? 1.0f : QSCALE;
        float f0 = exp2f(-(float)lr * L2_1E4_D32) * INV2PI;
        float f1 = exp2f(-(float)(16 + lr) * L2_1E4_D32) * INV2PI;
        #pragma unroll
        for (int i = 0; i < 4; ++i) {
            #pragma unroll
            for (int r = 0; r < 4; ++r) {
                int row = 64 * wm + 16 * i + 4 * lq + r;
                int n = n00 + row;
                float c0v, s0v, c1v, s1v;
                rope_cs(n, f0, &c0v, &s0v);
                rope_cs(n, f1, &c1v, &s1v);
                float q0 = acc[i][0][r], q1 = acc[i][1][r];
                float q2 = acc[i][2][r], q3 = acc[i][3][r];
                u.Css[row][64 * wn + lr]      = f2b(sc * (q0 * c0v - q2 * s0v));
                u.Css[row][64 * wn + 16 + lr] = f2b(sc * (q1 * c1v - q3 * s1v));
                u.Css[row][64 * wn + 32 + lr] = f2b(sc * (q2 * c0v + q0 * s0v));
                u.Css[row][64 * wn + 48 + lr] = f2b(sc * (q3 * c1v + q1 * s1v));
            }
        }
        __syncthreads();
        int row = tid >> 1, hh = tid & 1;
        int h = (e00 >> 6) + hh;
        int n = n00 + row;
        size_t base = (((size_t)(b * NH + h)) * SEQ + n) * HD;
        #pragma unroll
        for (int p = 0; p < 8; ++p)
            *(v8s*)&dst[base + 8 * p] = *(const v8s*)&u.Css[row][64 * hh + 8 * p];
    } else {
        // V transposed: Css_T[col][row], packed b64 along row (r contiguous)
        #pragma unroll
        for (int i = 0; i < 4; ++i) {
            #pragma unroll
            for (int j = 0; j < 4; ++j) {
                v4s t;
                #pragma unroll
                for (int r = 0; r < 4; ++r) t[r] = f2b(acc[i][j][r]);
                *(v4s*)&u.Css[64 * wn + 16 * j + lr][64 * wm + 16 * i + 4 * lq] = t;
            }
        }
        __syncthreads();
        int c = tid >> 1, half = (tid & 1) * 64;
        int h = (e00 + c) >> 6, d = (e00 + c) & 63;
        size_t base = (((size_t)(b * NH + h)) * HD + d) * SEQ + n00 + half;
        #pragma unroll
        for (int p = 0; p < 8; ++p)
            *(v8s*)&Vt[base + 8 * p] = *(const v8s*)&u.Css[c][half + 8 * p];
    }
}

// ---------------------------------------------------------------------------
// Kernel 2: flash attention, KEY-SPLIT wave decomposition (round-6 retry).
// 8 waves = 4 row-groups (wr) x 2 key-groups (wk): each wave owns 32 Q-rows x
// its 64-key half per 128-key chunk — halves the dominant LDS pools (kf and
// Vs fragment reads). Math validated on HW in round 5 (passed refcheck).
// Round-5 FAILED ON PERF ONLY: launch_bounds(512,4) = 128-reg UNIFIED
// (VGPR+AGPR, gfx950) budget; allocator's 64+64 split couldn't hold the
// larger live set -> scratch spills (WRITE_SIZE 9MB->156MB, 111us).
// Fix: (512,2) = 256-reg budget. LDS 66048B already caps residency at
// 2 blocks/CU = 16 waves/CU, so the relaxed floor costs no occupancy.
// ABORT CRITERION: WRITE_SIZE >> 9216 KB again => abandon key-split.
// Kept: T2 XOR-swizzle, key-permuted staging, fixed-max softmax (M=24),
// raw v_exp_f32, v_cvt_pk_bf16_f32, register prefetch.
// grid = (MTOT/128, NH) = 512 blocks.
// ---------------------------------------------------------------------------
#define SWZ(tile, row, bo) ((char*)&(tile)[row][0] + ((bo) ^ (((row) & 7) << 4)))

__global__ __launch_bounds__(512, 2) void attn_mfma(
    const short* __restrict__ Qb, const short* __restrict__ K,
    const short* __restrict__ Vt, const int* __restrict__ mask,
    short* __restrict__ O)
{
    const int m0 = blockIdx.x * 128, h = blockIdx.y;
    const int b = m0 >> 11, n0 = m0 & (SEQ - 1), bh = b * NH + h;
    const int tid = threadIdx.x;
    const int w = tid >> 6, lane = tid & 63, lq = lane >> 4, lr = lane & 15;
    const int wr = w >> 1, wk = w & 1;

    __shared__ short Ks[128][64];    // 16 KB, XOR-swizzled (key-permuted rows)
    __shared__ short Vs[64][128];    // 16 KB, XOR-swizzled ([d][128 true keys])
    __shared__ short Ps[128][128];   // 32 KB, XOR-swizzled ([qrow][128 true keys])
    __shared__ float mbias[128];     // 512 B, indexed by permuted storage row

    // ---- load Q A-fragments: rows 32wr+16it+lr, pre-scaled + RoPE'd ----
    const short* __restrict__ Qh = Qb + (size_t)bh * SEQ * HD;
    v8s aq[2][2];
    #pragma unroll
    for (int it = 0; it < 2; ++it)
        #pragma unroll
        for (int ks = 0; ks < 2; ++ks)
            aq[it][ks] = *(const v8s*)&Qh[(size_t)(n0 + 32 * wr + 16 * it + lr) * HD
                                          + 32 * ks + 8 * lq];

    float lacc[2][4];
    v4f o[2][4];
    #pragma unroll
    for (int it = 0; it < 2; ++it)
        #pragma unroll
        for (int nt = 0; nt < 4; ++nt) {
            lacc[it][nt] = 0.f;
            for (int r = 0; r < 4; ++r) o[it][nt][r] = 0.f;
        }

    // staging indices: K 128 rows x 64 d ; V 64 d x 128 keys (all waves stage)
    const int kr = tid >> 2, kc = (tid & 3) * 16;     // kc in shorts (global)
    const int kb = 32 * (tid & 3);                    // LDS byte offset
    const int krh = kr & 63;
    const int pkr = 64 * (kr >> 6) + 16 * (krh & 3) + (krh >> 2);  // permuted
    const int vr = tid >> 3, vc = (tid & 7) * 16;
    const int vb = 32 * (tid & 7);
    const short* __restrict__ Kb = K + (size_t)bh * SEQ * HD;
    const short* __restrict__ Vb = Vt + (size_t)bh * HD * SEQ;

    // prefetch chunk 0
    v8s k1 = *(const v8s*)&Kb[(size_t)kr * HD + kc];
    v8s k2 = *(const v8s*)&Kb[(size_t)kr * HD + kc + 8];
    v8s v1 = *(const v8s*)&Vb[(size_t)vr * SEQ + vc];
    v8s v2 = *(const v8s*)&Vb[(size_t)vr * SEQ + vc + 8];
    int mnext = ((tid & 3) == 0) ? mask[b * SEQ + kr] : 0;

    for (int c0 = 0; c0 < SEQ; c0 += 128) {
        __syncthreads();                      // prev chunk LDS reads done
        *(v8s*)SWZ(Ks, pkr, kb)      = k1;
        *(v8s*)SWZ(Ks, pkr, kb + 16) = k2;
        *(v8s*)SWZ(Vs, vr, vb)       = v1;
        *(v8s*)SWZ(Vs, vr, vb + 16)  = v2;
        if ((tid & 3) == 0) mbias[pkr] = mnext ? -24.0f : -1e30f;
        __syncthreads();
        if (c0 + 128 < SEQ) {                 // prefetch next chunk
            k1 = *(const v8s*)&Kb[(size_t)(c0 + 128 + kr) * HD + kc];
            k2 = *(const v8s*)&Kb[(size_t)(c0 + 128 + kr) * HD + kc + 8];
            v1 = *(const v8s*)&Vb[(size_t)vr * SEQ + c0 + 128 + vc];
            v2 = *(const v8s*)&Vb[(size_t)vr * SEQ + c0 + 128 + vc + 8];
            if ((tid & 3) == 0) mnext = mask[b * SEQ + c0 + 128 + kr];
        }

        // ---- QK^T + P for this wave's 64-key half, nt in pairs ----
        // storage row 64wk+16nt+lr holds key 64wk+4lr+nt (permutation);
        // S col (nt,lr) <-> true key 64wk+4lr+nt.
        #pragma unroll
        for (int ntp = 0; ntp < 2; ++ntp) {
            v8s kf0[2], kf1[2];
            #pragma unroll
            for (int ks = 0; ks < 2; ++ks) {
                kf0[ks] = *(const v8s*)SWZ(Ks, 64 * wk + 32 * ntp + lr,
                                           64 * ks + 16 * lq);
                kf1[ks] = *(const v8s*)SWZ(Ks, 64 * wk + 32 * ntp + 16 + lr,
                                           64 * ks + 16 * lq);
            }
            float bias0 = mbias[64 * wk + 32 * ntp + lr];
            float bias1 = mbias[64 * wk + 32 * ntp + 16 + lr];
            #pragma unroll
            for (int it = 0; it < 2; ++it) {
                v4f s0, s1;
                #pragma unroll
                for (int r = 0; r < 4; ++r) { s0[r] = 0.f; s1[r] = 0.f; }
                #pragma unroll
                for (int ks = 0; ks < 2; ++ks) {
                    s0 = MFMA16(aq[it][ks], kf0[ks], s0);
                    s1 = MFMA16(aq[it][ks], kf1[ks], s1);
                }
                // p = exp2(s + bias); 4B packed write: keys 4lr+2ntp, +1
                #pragma unroll
                for (int r = 0; r < 4; ++r) {
                    float p0 = fexp2(s0[r] + bias0);
                    float p1 = fexp2(s1[r] + bias1);
                    lacc[it][r] += p0 + p1;
                    unsigned uu;
                    asm("v_cvt_pk_bf16_f32 %0, %1, %2" : "=v"(uu) : "v"(p0), "v"(p1));
                    int qrow = 32 * wr + 16 * it + 4 * lq + r;
                    *(unsigned*)SWZ(Ps, qrow, 128 * wk + 8 * lr + 4 * ntp) = uu;
                }
            }
        }

        // ---- O += P @ V over this wave's 64 keys (Ps rows wave-owned) ----
        #pragma unroll
        for (int ks = 0; ks < 2; ++ks) {
            v8s a0 = *(const v8s*)SWZ(Ps, 32 * wr + lr,
                                      128 * wk + 64 * ks + 16 * lq);
            v8s a1 = *(const v8s*)SWZ(Ps, 32 * wr + 16 + lr,
                                      128 * wk + 64 * ks + 16 * lq);
            #pragma unroll
            for (int nt = 0; nt < 4; ++nt) {
                v8s vf = *(const v8s*)SWZ(Vs, 16 * nt + lr,
                                          128 * wk + 64 * ks + 16 * lq);
                o[0][nt] = MFMA16(a0, vf, o[0][nt]);
                o[1][nt] = MFMA16(a1, vf, o[1][nt]);
            }
        }
    }

    // ---- intra-wave row sums over this wave's keys (lanes lr 0..15) ----
    #pragma unroll
    for (int it = 0; it < 2; ++it)
        #pragma unroll
        for (int r = 0; r < 4; ++r) {
            float l = lacc[it][r];
            l += __shfl_xor(l, 1);
            l += __shfl_xor(l, 2);
            l += __shfl_xor(l, 4);
            l += __shfl_xor(l, 8);
            lacc[it][r] = l;
        }

    // ---- cross-wk merge through LDS scratch (Ps/Ks reuse) ----
    __syncthreads();                          // all PV reads finished
    float* mO = (float*)&Ps[0][0];            // 4wr x 8tile x 64lane x v4f = 32 KB
    float* mL = (float*)&Ks[0][0];            // 4wr x 8 x 64lane f32     =  8 KB
    if (wk == 1) {
        #pragma unroll
        for (int it = 0; it < 2; ++it) {
            #pragma unroll
            for (int nt = 0; nt < 4; ++nt)
                *(v4f*)&mO[(((wr * 8 + it * 4 + nt) * 64) + lane) * 4] = o[it][nt];
            #pragma unroll
            for (int r = 0; r < 4; ++r)
                mL[(wr * 8 + it * 4 + r) * 64 + lane] = lacc[it][r];
        }
    }
    __syncthreads();
    if (wk == 0) {
        #pragma unroll
        for (int it = 0; it < 2; ++it) {
            #pragma unroll
            for (int nt = 0; nt < 4; ++nt) {
                v4f t = *(const v4f*)&mO[(((wr * 8 + it * 4 + nt) * 64) + lane) * 4];
                #pragma unroll
                for (int r = 0; r < 4; ++r) o[it][nt][r] += t[r];
            }
            #pragma unroll
            for (int r = 0; r < 4; ++r) {
                float l = lacc[it][r] + mL[(wr * 8 + it * 4 + r) * 64 + lane];
                float inv = (l > 0.f) ? 1.f / l : 0.f;   // all-masked rows -> 0
                int qrow = 32 * wr + 16 * it + 4 * lq + r;
                #pragma unroll
                for (int nt = 0; nt < 4; ++nt)
                    O[(size_t)(m0 + qrow) * DM + h * HD + 16 * nt + lr] =
                        f2b(o[it][nt][r] * inv);
            }
        }
    }
}

// ---------------------------------------------------------------------------
// Kernel 3: out = O @ Wo^T, 64x128 MFMA tile (512 blocks), fp32 store.
// Round-3 structure (single-buffer; dbuf was neutral — see kernel 1).
// grid = (MTOT/64, DM/128).
// ---------------------------------------------------------------------------
__global__ __launch_bounds__(256, 2) void oproj_mfma(
    const short* __restrict__ O, const short* __restrict__ Wob,
    float* __restrict__ out)
{
    const int m0 = blockIdx.x * 64, e00 = blockIdx.y * 128;
    const int tid = threadIdx.x;
    const int w = tid >> 6, lane = tid & 63, lq = lane >> 4, lr = lane & 15;

    __shared__ short As[64][32];    // 4 KB
    __shared__ short Bs[128][32];   // 8 KB

    v4f acc[4][2];
    #pragma unroll
    for (int i = 0; i < 4; ++i)
        for (int j = 0; j < 2; ++j)
            for (int r = 0; r < 4; ++r) acc[i][j][r] = 0.f;

    const int gr = lane >> 2, gc = 8 * (lane & 3);
    for (int k0 = 0; k0 < DM; k0 += 32) {
        __syncthreads();
        gload16(&O[(size_t)(m0 + 16 * w + gr) * DM + k0 + gc],         &As[16 * w][0]);
        gload16(&Wob[(size_t)(e00 + 32 * w      + gr) * DM + k0 + gc], &Bs[32 * w][0]);
        gload16(&Wob[(size_t)(e00 + 32 * w + 16 + gr) * DM + k0 + gc], &Bs[32 * w + 16][0]);
        __syncthreads();
        v8s af[4], bf[2];
        #pragma unroll
        for (int i = 0; i < 4; ++i)
            af[i] = *(const v8s*)&As[16 * i + lr][8 * lq];
        #pragma unroll
        for (int j = 0; j < 2; ++j)
            bf[j] = *(const v8s*)&Bs[32 * w + 16 * j + lr][8 * lq];
        #pragma unroll
        for (int i = 0; i < 4; ++i)
            #pragma unroll
            for (int j = 0; j < 2; ++j)
                acc[i][j] = MFMA16(af[i], bf[j], acc[i][j]);
    }

    #pragma unroll
    for (int i = 0; i < 4; ++i)
        #pragma unroll
        for (int r = 0; r < 4; ++r) {
            int m = m0 + 16 * i + 4 * lq + r;
            #pragma unroll
            for (int j = 0; j < 2; ++j)
                out[(size_t)m * DM + e00 + 32 * w + 16 * j + lr] = acc[i][j][r];
        }
}

// ---------------------------------------------------------------------------
extern "C" void kernel_launch(void* const* d_in, const int* in_sizes, int n_in,
                              void* d_out, int out_size, void* d_ws, size_t ws_size,
                              hipStream_t stream)
{
    const float* x    = (const float*)d_in[0];
    const int*   mask = (const int*)d_in[1];
    const float* Wq   = (const float*)d_in[2];
    const float* Wk   = (const float*)d_in[3];
    const float* Wv   = (const float*)d_in[4];
    const float* Wo   = (const float*)d_in[5];
    float* out = (float*)d_out;

    // ws (24 MiB of shorts): xb | Wqb | Wkb | Wvb | Wob | Qb
    //   xb region is reused for O after qkv_rope (attn no longer reads x).
    short* xb  = (short*)d_ws;                    // 8 MB (x, then O)
    short* Wqb = xb  + (size_t)MTOT * DM;         // 2 MB each
    short* Wkb = Wqb + (size_t)DM * DM;
    short* Wvb = Wkb + (size_t)DM * DM;
    short* Wob = Wvb + (size_t)DM * DM;
    short* Qb  = Wob + (size_t)DM * DM;           // 8 MB
    short* O   = xb;                              // alias (post-qkv)
    // d_out (16 MiB) doubles as K/Vt scratch until the final projection
    short* K  = (short*)d_out;                    // 8 MB
    short* Vt = K + (size_t)MTOT * DM;            // 8 MB

    cvt_all_kernel<<<4096, 256, 0, stream>>>(x, Wq, Wk, Wv, Wo, xb);

    dim3 g1(MTOT / 128, DM / 128, 3);
    qkv_rope_mfma<<<g1, 256, 0, stream>>>(xb, Wqb, Wkb, Wvb, K, Vt, Qb);

    dim3 g2(MTOT / 128, NH);
    attn_mfma<<<g2, 512, 0, stream>>>(Qb, K, Vt, mask, O);

    dim3 g3(MTOT / 64, DM / 128);
    oproj_mfma<<<g3, 256, 0, stream>>>(O, Wob, out);
}

// Round 7
// 189.474 us; speedup vs baseline: 1.2856x; 1.0319x over previous
//
#include <hip/hip_runtime.h>
#include <math.h>

#define BATCH 2
#define SEQ   2048
#define DM    1024
#define NH    16
#define HD    64
#define MTOT  (BATCH*SEQ)            // 4096

typedef short v8s __attribute__((ext_vector_type(8)));   // 8 bf16 = 4 VGPR
typedef short v4s __attribute__((ext_vector_type(4)));
typedef float v4f __attribute__((ext_vector_type(4)));

#define MFMA16(a, b, c) __builtin_amdgcn_mfma_f32_16x16x32_bf16((a), (b), (c), 0, 0, 0)

__device__ __forceinline__ short f2b(float f) {   // fp32->bf16, round-half-up
    union { float f; unsigned u; } v; v.f = f;
    return (short)((v.u + 0x8000u) >> 16);
}

// raw v_exp_f32 (exp2): OCML exp2f adds a denormal-guard sequence (~6 instr);
// the hot softmax path only needs the HW instruction. exp2(-1e30) -> 0 in HW.
__device__ __forceinline__ float fexp2(float x) {
    float r; asm("v_exp_f32 %0, %1" : "=v"(r) : "v"(x)); return r;
}

// async global->LDS, 16B per lane. dst must be wave-uniform base; HW adds lane*16.
__device__ __forceinline__ void gload16(const void* g, void* lds) {
    __builtin_amdgcn_global_load_lds(
        (const __attribute__((address_space(1))) void*)g,
        (__attribute__((address_space(3))) void*)lds, 16, 0, 0);
}

// native RoPE sincos via revolutions + fract (no library range reduction)
__device__ __forceinline__ void rope_cs(int n, float f_rev, float* c, float* s) {
    float rev = (float)n * f_rev;
    float t = rev - floorf(rev);
    float ang = t * 6.283185307179586f;
    *c = __cosf(ang);
    *s = __sinf(ang);
}

#define L2_1E4_D32 0.4152410118609203f   // log2(10000)/32
#define INV2PI     0.15915494309189535f
#define QSCALE     0.18033688011112042f  // 0.125 * log2(e)

// ---------------------------------------------------------------------------
// Kernel 0: fused fp32 -> bf16 convert for x | Wq | Wk | Wv | Wo into ws base.
// ---------------------------------------------------------------------------
__global__ __launch_bounds__(256) void cvt_all_kernel(
    const float* __restrict__ x,  const float* __restrict__ wq,
    const float* __restrict__ wk, const float* __restrict__ wv,
    const float* __restrict__ wo, short* __restrict__ dst)
{
    int i = blockIdx.x * 256 + threadIdx.x;            // < 1 Mi
    const float* src; int off;
    if (i < (1 << 19)) { src = x; off = i; }
    else {
        int j = i - (1 << 19);
        int wsel = j >> 17;
        off = j & ((1 << 17) - 1);
        src = (wsel == 0) ? wq : (wsel == 1) ? wk : (wsel == 2) ? wv : wo;
    }
    const float4* s4 = (const float4*)src;
    float4 a = s4[2 * off], b = s4[2 * off + 1];
    v8s p;
    p[0] = f2b(a.x); p[1] = f2b(a.y); p[2] = f2b(a.z); p[3] = f2b(a.w);
    p[4] = f2b(b.x); p[5] = f2b(b.y); p[6] = f2b(b.z); p[7] = f2b(b.w);
    *(v8s*)&dst[8 * i] = p;
}

// ---------------------------------------------------------------------------
// Kernel 1: Q/K/V projections, 128x128 MFMA tile. Native-sincos RoPE.
// Round-7: BK=64 — stage BOTH 32-K sub-tiles per barrier pair (8 gload16),
// then two compute halves. Halves the #barriers and the per-step vmcnt(0)
// latency exposures vs BK=32; register pressure unchanged (compute still
// per-32-K half). Sub-tiles stay [2][128][32] (64-B row stride) — a flat
// [128][64] tile would be a 4-way bank conflict on fragment reads (128-B
// stride puts all 16 lr-lanes in one bank quad).
//   z=0: K = RoPE(x @ Wk^T)        -> [bh][key][d]
//   z=1: V = x @ Wv^T (transposed) -> Vt[bh][d][key]
//   z=2: Q = QSCALE*RoPE(x @ Wq^T) -> Qb[bh][row][d]
// grid = (MTOT/128, DM/128, 3) = 768 blocks, 3/CU (union still Css-bound).
// ---------------------------------------------------------------------------
__global__ __launch_bounds__(256, 3) void qkv_rope_mfma(
    const short* __restrict__ xb, const short* __restrict__ Wqb,
    const short* __restrict__ Wkb, const short* __restrict__ Wvb,
    short* __restrict__ K, short* __restrict__ Vt, short* __restrict__ Qb)
{
    const int zz = blockIdx.z;
    const short* __restrict__ Wb = (zz == 0) ? Wkb : (zz == 1) ? Wvb : Wqb;
    const int m0 = blockIdx.x * 128, e00 = blockIdx.y * 128;
    const int tid = threadIdx.x;
    const int w = tid >> 6, lane = tid & 63, lq = lane >> 4, lr = lane & 15;
    const int wm = w >> 1, wn = w & 1;

    __shared__ union {
        struct { short As[2][128][32]; short Bs[2][128][32]; } p1;  // 32 KB
        short Css[128][136];                                         // 34 KB
    } u;

    v4f acc[4][4];
    #pragma unroll
    for (int i = 0; i < 4; ++i)
        for (int j = 0; j < 4; ++j)
            for (int r = 0; r < 4; ++r) acc[i][j][r] = 0.f;

    const int gr = lane >> 2, gc = 8 * (lane & 3);
    for (int k0 = 0; k0 < DM; k0 += 64) {
        __syncthreads();   // prev iter LDS reads done
        #pragma unroll
        for (int ks = 0; ks < 2; ++ks) {
            gload16(&xb[(size_t)(m0 + 32 * w      + gr) * DM + k0 + 32 * ks + gc],
                    &u.p1.As[ks][32 * w][0]);
            gload16(&xb[(size_t)(m0 + 32 * w + 16 + gr) * DM + k0 + 32 * ks + gc],
                    &u.p1.As[ks][32 * w + 16][0]);
            gload16(&Wb[(size_t)(e00 + 32 * w      + gr) * DM + k0 + 32 * ks + gc],
                    &u.p1.Bs[ks][32 * w][0]);
            gload16(&Wb[(size_t)(e00 + 32 * w + 16 + gr) * DM + k0 + 32 * ks + gc],
                    &u.p1.Bs[ks][32 * w + 16][0]);
        }
        __syncthreads();   // vmcnt drained before barrier -> both sub-tiles visible
        #pragma unroll
        for (int ks = 0; ks < 2; ++ks) {
            v8s af[4], bf[4];
            #pragma unroll
            for (int i = 0; i < 4; ++i)
                af[i] = *(const v8s*)&u.p1.As[ks][64 * wm + 16 * i + lr][8 * lq];
            #pragma unroll
            for (int j = 0; j < 4; ++j)
                bf[j] = *(const v8s*)&u.p1.Bs[ks][64 * wn + 16 * j + lr][8 * lq];
            #pragma unroll
            for (int i = 0; i < 4; ++i)
                #pragma unroll
                for (int j = 0; j < 4; ++j)
                    acc[i][j] = MFMA16(af[i], bf[j], acc[i][j]);
        }
    }
    __syncthreads();   // k-loop LDS reads done before Css overwrite

    const int b = m0 >> 11, n00 = m0 & (SEQ - 1);

    if (zz != 1) {
        // RoPE in-register (cols of this wave = one head; pairs nt <-> nt^2)
        short* __restrict__ dst = (zz == 0) ? K : Qb;
        const float sc = (zz == 0) ? 1.0f : QSCALE;
        float f0 = exp2f(-(float)lr * L2_1E4_D32) * INV2PI;
        float f1 = exp2f(-(float)(16 + lr) * L2_1E4_D32) * INV2PI;
        #pragma unroll
        for (int i = 0; i < 4; ++i) {
            #pragma unroll
            for (int r = 0; r < 4; ++r) {
                int row = 64 * wm + 16 * i + 4 * lq + r;
                int n = n00 + row;
                float c0v, s0v, c1v, s1v;
                rope_cs(n, f0, &c0v, &s0v);
                rope_cs(n, f1, &c1v, &s1v);
                float q0 = acc[i][0][r], q1 = acc[i][1][r];
                float q2 = acc[i][2][r], q3 = acc[i][3][r];
                u.Css[row][64 * wn + lr]      = f2b(sc * (q0 * c0v - q2 * s0v));
                u.Css[row][64 * wn + 16 + lr] = f2b(sc * (q1 * c1v - q3 * s1v));
                u.Css[row][64 * wn + 32 + lr] = f2b(sc * (q2 * c0v + q0 * s0v));
                u.Css[row][64 * wn + 48 + lr] = f2b(sc * (q3 * c1v + q1 * s1v));
            }
        }
        __syncthreads();
        int row = tid >> 1, hh = tid & 1;
        int h = (e00 >> 6) + hh;
        int n = n00 + row;
        size_t base = (((size_t)(b * NH + h)) * SEQ + n) * HD;
        #pragma unroll
        for (int p = 0; p < 8; ++p)
            *(v8s*)&dst[base + 8 * p] = *(const v8s*)&u.Css[row][64 * hh + 8 * p];
    } else {
        // V transposed: Css_T[col][row], packed b64 along row (r contiguous)
        #pragma unroll
        for (int i = 0; i < 4; ++i) {
            #pragma unroll
            for (int j = 0; j < 4; ++j) {
                v4s t;
                #pragma unroll
                for (int r = 0; r < 4; ++r) t[r] = f2b(acc[i][j][r]);
                *(v4s*)&u.Css[64 * wn + 16 * j + lr][64 * wm + 16 * i + 4 * lq] = t;
            }
        }
        __syncthreads();
        int c = tid >> 1, half = (tid & 1) * 64;
        int h = (e00 + c) >> 6, d = (e00 + c) & 63;
        size_t base = (((size_t)(b * NH + h)) * HD + d) * SEQ + n00 + half;
        #pragma unroll
        for (int p = 0; p < 8; ++p)
            *(v8s*)&Vt[base + 8 * p] = *(const v8s*)&u.Css[c][half + 8 * p];
    }
}

// ---------------------------------------------------------------------------
// Kernel 2: flash attention — EXACT round-3 version (best measured: 57.9us).
// Round-5/6 key-split abandoned: halved LDS traffic but 66KB LDS halved
// residency (Occupancy 34->19%) -> net loss (65.8us).
// 128-row Q-tile, 512 thr / 8 waves (one 16-row strip each). KCHUNK=128.
// Fixed-max softmax (M=24 in mbias), key-permuted K staging, K/V fragments
// hoisted, register prefetch, raw v_exp_f32, v_cvt_pk_bf16_f32 P-pack,
// T2 XOR-swizzle on linear 128B rows (conflicts 1.30e7 -> 6.4e6).
// launch_bounds min-waves MUST stay 4: (512,6) forces spills (round-1).
// grid = (MTOT/128, NH) = 512 blocks.
// ---------------------------------------------------------------------------
#define SWZ(tile, row, bo) ((char*)&(tile)[row][0] + ((bo) ^ (((row) & 7) << 4)))

__global__ __launch_bounds__(512, 4) void attn_mfma(
    const short* __restrict__ Qb, const short* __restrict__ K,
    const short* __restrict__ Vt, const int* __restrict__ mask,
    short* __restrict__ O)
{
    const int m0 = blockIdx.x * 128, h = blockIdx.y;
    const int b = m0 >> 11, n0 = m0 & (SEQ - 1), bh = b * NH + h;
    const int tid = threadIdx.x;
    const int w = tid >> 6, lane = tid & 63, lq = lane >> 4, lr = lane & 15;

    __shared__ short Ks[128][64];    // 16 KB, XOR-swizzled (key-permuted rows)
    __shared__ short Vs[64][128];    // 16 KB, XOR-swizzled ([d][128 keys])
    __shared__ short Ps[128][64];    // 16 KB, XOR-swizzled (wave-private strips)
    __shared__ float mbias[128];     // 512 B, indexed by permuted storage row

    // ---- load Q A-fragments (rows 16w+lr, pre-scaled + RoPE'd) ----
    const short* __restrict__ Qh = Qb + (size_t)bh * SEQ * HD;
    v8s aq[2];
    #pragma unroll
    for (int ks = 0; ks < 2; ++ks)
        aq[ks] = *(const v8s*)&Qh[(size_t)(n0 + 16 * w + lr) * HD + 32 * ks + 8 * lq];

    float lacc[4] = {0.f, 0.f, 0.f, 0.f};
    v4f o[4];
    #pragma unroll
    for (int nt = 0; nt < 4; ++nt)
        for (int r = 0; r < 4; ++r) o[nt][r] = 0.f;

    // staging indices: K 128 rows x 64 d ; V 64 d x 128 keys
    const int kr = tid >> 2, kc = (tid & 3) * 16;     // kc in shorts (global)
    const int kb = 32 * (tid & 3);                    // LDS byte offset
    const int krh = kr & 63;
    const int pkr = 64 * (kr >> 6) + 16 * (krh & 3) + (krh >> 2);  // permuted
    const int vr = tid >> 3, vc = (tid & 7) * 16;
    const int vb = 32 * (tid & 7);
    const short* __restrict__ Kb = K + (size_t)bh * SEQ * HD;
    const short* __restrict__ Vb = Vt + (size_t)bh * HD * SEQ;

    // prefetch chunk 0
    v8s k1 = *(const v8s*)&Kb[(size_t)kr * HD + kc];
    v8s k2 = *(const v8s*)&Kb[(size_t)kr * HD + kc + 8];
    v8s v1 = *(const v8s*)&Vb[(size_t)vr * SEQ + vc];
    v8s v2 = *(const v8s*)&Vb[(size_t)vr * SEQ + vc + 8];
    int mnext = ((tid & 3) == 0) ? mask[b * SEQ + kr] : 0;

    for (int c0 = 0; c0 < SEQ; c0 += 128) {
        __syncthreads();                      // prev chunk LDS reads done
        *(v8s*)SWZ(Ks, pkr, kb)      = k1;
        *(v8s*)SWZ(Ks, pkr, kb + 16) = k2;
        *(v8s*)SWZ(Vs, vr, vb)       = v1;
        *(v8s*)SWZ(Vs, vr, vb + 16)  = v2;
        if ((tid & 3) == 0) mbias[pkr] = mnext ? -24.0f : -1e30f;
        __syncthreads();
        if (c0 + 128 < SEQ) {                 // prefetch next chunk
            k1 = *(const v8s*)&Kb[(size_t)(c0 + 128 + kr) * HD + kc];
            k2 = *(const v8s*)&Kb[(size_t)(c0 + 128 + kr) * HD + kc + 8];
            v1 = *(const v8s*)&Vb[(size_t)vr * SEQ + c0 + 128 + vc];
            v2 = *(const v8s*)&Vb[(size_t)vr * SEQ + c0 + 128 + vc + 8];
            if ((tid & 3) == 0) mnext = mask[b * SEQ + c0 + 128 + kr];
        }

        #pragma unroll
        for (int half = 0; half < 2; ++half) {
            // hoist K fragments; S col (nt,lr) <-> key 64*half + 4*lr + nt
            v8s kf[2][4];
            #pragma unroll
            for (int ks = 0; ks < 2; ++ks)
                #pragma unroll
                for (int nt = 0; nt < 4; ++nt)
                    kf[ks][nt] = *(const v8s*)SWZ(Ks, 64 * half + 16 * nt + lr,
                                                  64 * ks + 16 * lq);
            float bias[4];
            #pragma unroll
            for (int nt = 0; nt < 4; ++nt)
                bias[nt] = mbias[64 * half + 16 * nt + lr];

            v4f sv[4];
            #pragma unroll
            for (int nt = 0; nt < 4; ++nt)
                for (int r = 0; r < 4; ++r) sv[nt][r] = 0.f;
            #pragma unroll
            for (int ks = 0; ks < 2; ++ks)
                #pragma unroll
                for (int nt = 0; nt < 4; ++nt)
                    sv[nt] = MFMA16(aq[ks], kf[ks][nt], sv[nt]);

            // p = exp2(s + bias); v_cvt_pk packed write (keys 4lr..4lr+3)
            #pragma unroll
            for (int r = 0; r < 4; ++r) {
                float p0 = fexp2(sv[0][r] + bias[0]);
                float p1 = fexp2(sv[1][r] + bias[1]);
                float p2 = fexp2(sv[2][r] + bias[2]);
                float p3 = fexp2(sv[3][r] + bias[3]);
                lacc[r] += (p0 + p1) + (p2 + p3);
                unsigned u0, u1;
                asm("v_cvt_pk_bf16_f32 %0, %1, %2" : "=v"(u0) : "v"(p0), "v"(p1));
                asm("v_cvt_pk_bf16_f32 %0, %1, %2" : "=v"(u1) : "v"(p2), "v"(p3));
                uint2 pk; pk.x = u0; pk.y = u1;
                int prow = 16 * w + 4 * lq + r;
                *(uint2*)SWZ(Ps, prow, 8 * lr) = pk;   // 8B stays within 16B slot
            }
            // O += P @ V_half  (Ps strip wave-private; V cols 64*half+...)
            #pragma unroll
            for (int ks = 0; ks < 2; ++ks) {
                v8s a = *(const v8s*)SWZ(Ps, 16 * w + lr, 64 * ks + 16 * lq);
                #pragma unroll
                for (int nt = 0; nt < 4; ++nt) {
                    v8s vf = *(const v8s*)SWZ(Vs, 16 * nt + lr,
                                              128 * half + 64 * ks + 16 * lq);
                    o[nt] = MFMA16(a, vf, o[nt]);
                }
            }
        }
    }

    // ---- finalize: one butterfly per row; all-masked rows -> l=0 -> 0 ----
    #pragma unroll
    for (int r = 0; r < 4; ++r) {
        float l = lacc[r];
        l += __shfl_xor(l, 1);
        l += __shfl_xor(l, 2);
        l += __shfl_xor(l, 4);
        l += __shfl_xor(l, 8);
        float inv = (l > 0.f) ? 1.f / l : 0.f;
        int qrow = 16 * w + 4 * lq + r;
        #pragma unroll
        for (int nt = 0; nt < 4; ++nt)
            O[(size_t)(m0 + qrow) * DM + h * HD + 16 * nt + lr] =
                f2b(o[nt][r] * inv);
    }
}

// ---------------------------------------------------------------------------
// Kernel 3: out = O @ Wo^T, 64x128 MFMA tile (512 blocks), fp32 store.
// Round-7: BK=64 (same sub-tile scheme as kernel 1). LDS 12 -> 24 KB.
// grid = (MTOT/64, DM/128).
// ---------------------------------------------------------------------------
__global__ __launch_bounds__(256, 2) void oproj_mfma(
    const short* __restrict__ O, const short* __restrict__ Wob,
    float* __restrict__ out)
{
    const int m0 = blockIdx.x * 64, e00 = blockIdx.y * 128;
    const int tid = threadIdx.x;
    const int w = tid >> 6, lane = tid & 63, lq = lane >> 4, lr = lane & 15;

    __shared__ short As[2][64][32];    // 8 KB
    __shared__ short Bs[2][128][32];   // 16 KB

    v4f acc[4][2];
    #pragma unroll
    for (int i = 0; i < 4; ++i)
        for (int j = 0; j < 2; ++j)
            for (int r = 0; r < 4; ++r) acc[i][j][r] = 0.f;

    const int gr = lane >> 2, gc = 8 * (lane & 3);
    for (int k0 = 0; k0 < DM; k0 += 64) {
        __syncthreads();
        #pragma unroll
        for (int ks = 0; ks < 2; ++ks) {
            gload16(&O[(size_t)(m0 + 16 * w + gr) * DM + k0 + 32 * ks + gc],
                    &As[ks][16 * w][0]);
            gload16(&Wob[(size_t)(e00 + 32 * w      + gr) * DM + k0 + 32 * ks + gc],
                    &Bs[ks][32 * w][0]);
            gload16(&Wob[(size_t)(e00 + 32 * w + 16 + gr) * DM + k0 + 32 * ks + gc],
                    &Bs[ks][32 * w + 16][0]);
        }
        __syncthreads();
        #pragma unroll
        for (int ks = 0; ks < 2; ++ks) {
            v8s af[4], bf[2];
            #pragma unroll
            for (int i = 0; i < 4; ++i)
                af[i] = *(const v8s*)&As[ks][16 * i + lr][8 * lq];
            #pragma unroll
            for (int j = 0; j < 2; ++j)
                bf[j] = *(const v8s*)&Bs[ks][32 * w + 16 * j + lr][8 * lq];
            #pragma unroll
            for (int i = 0; i < 4; ++i)
                #pragma unroll
                for (int j = 0; j < 2; ++j)
                    acc[i][j] = MFMA16(af[i], bf[j], acc[i][j]);
        }
    }

    #pragma unroll
    for (int i = 0; i < 4; ++i)
        #pragma unroll
        for (int r = 0; r < 4; ++r) {
            int m = m0 + 16 * i + 4 * lq + r;
            #pragma unroll
            for (int j = 0; j < 2; ++j)
                out[(size_t)m * DM + e00 + 32 * w + 16 * j + lr] = acc[i][j][r];
        }
}

// ---------------------------------------------------------------------------
extern "C" void kernel_launch(void* const* d_in, const int* in_sizes, int n_in,
                              void* d_out, int out_size, void* d_ws, size_t ws_size,
                              hipStream_t stream)
{
    const float* x    = (const float*)d_in[0];
    const int*   mask = (const int*)d_in[1];
    const float* Wq   = (const float*)d_in[2];
    const float* Wk   = (const float*)d_in[3];
    const float* Wv   = (const float*)d_in[4];
    const float* Wo   = (const float*)d_in[5];
    float* out = (float*)d_out;

    // ws (24 MiB of shorts): xb | Wqb | Wkb | Wvb | Wob | Qb
    //   xb region is reused for O after qkv_rope (attn no longer reads x).
    short* xb  = (short*)d_ws;                    // 8 MB (x, then O)
    short* Wqb = xb  + (size_t)MTOT * DM;         // 2 MB each
    short* Wkb = Wqb + (size_t)DM * DM;
    short* Wvb = Wkb + (size_t)DM * DM;
    short* Wob = Wvb + (size_t)DM * DM;
    short* Qb  = Wob + (size_t)DM * DM;           // 8 MB
    short* O   = xb;                              // alias (post-qkv)
    // d_out (16 MiB) doubles as K/Vt scratch until the final projection
    short* K  = (short*)d_out;                    // 8 MB
    short* Vt = K + (size_t)MTOT * DM;            // 8 MB

    cvt_all_kernel<<<4096, 256, 0, stream>>>(x, Wq, Wk, Wv, Wo, xb);

    dim3 g1(MTOT / 128, DM / 128, 3);
    qkv_rope_mfma<<<g1, 256, 0, stream>>>(xb, Wqb, Wkb, Wvb, K, Vt, Qb);

    dim3 g2(MTOT / 128, NH);
    attn_mfma<<<g2, 512, 0, stream>>>(Qb, K, Vt, mask, O);

    dim3 g3(MTOT / 64, DM / 128);
    oproj_mfma<<<g3, 256, 0, stream>>>(O, Wob, out);
}